// Round 10
// baseline (600.895 us; speedup 1.0000x reference)
//
#include <hip/hip_runtime.h>
#include <hip/hip_bf16.h>
#include <cmath>

// ---------------------------------------------------------------------------
// GCN forward (R19):
//   R18 (586us) + agg128_i8 rewritten to the R11-proven wave-uniform gather:
//   readfirstlane -> SGPR row base, ushort/lane (64x2B = one 128B row per
//   instruction, saddr form), 16 rows in flight, masked tail. R10 measured
//   divergent addressing costs ~35% on this exact pattern (agg_i8 147 vs
//   109us); agg128 was the last divergent-gather kernel.
//   All other kernels byte-identical to R18.
// ---------------------------------------------------------------------------

typedef unsigned short u16;
typedef __attribute__((ext_vector_type(8))) short short8;
typedef __attribute__((ext_vector_type(4))) float f32x4;

#define BSHIFT 10                   // 1024 nodes per bucket
#define BNODES (1 << BSHIFT)
#define ECAP   36864                // per-bucket edge capacity (mean ~32.7k)
#define BMASK 0x00FF00FFu

__device__ __forceinline__ u16 f2bf(float f) {
    unsigned int u = __float_as_uint(f);
    u += 0x7fffu + ((u >> 16) & 1u);        // round-to-nearest-even
    return (u16)(u >> 16);
}

__device__ __forceinline__ int q8(float v) {   // clip to [-127,127], round
    return (int)rintf(fminf(fmaxf(v, -127.0f), 127.0f));
}

// ---------------- graph preprocessing ----------------

__global__ __launch_bounds__(128) void init_gcur_kernel(
        int* __restrict__ gcur, int nb) {
    int b = blockIdx.x * 128 + threadIdx.x;
    if (b < nb) gcur[b] = b * ECAP;
}

// Phase A: group edges by bucket (dst>>BSHIFT) into fixed-capacity regions of
// ebuf, packed src|dstlow<<17. LDS ranks + one global atomic per bucket/round.
__global__ __launch_bounds__(256) void bucketize_kernel(
        const int* __restrict__ src, const int* __restrict__ dst,
        int* __restrict__ gcur, unsigned int* __restrict__ ebuf, int E) {
    __shared__ int cnt[128];
    __shared__ int base[128];
    int tid = threadIdx.x;
    int chunk0 = blockIdx.x * 8192;
    int cend = min(chunk0 + 8192, E);
    for (int r0 = chunk0; r0 < cend; r0 += 2048) {
        if (tid < 128) cnt[tid] = 0;
        __syncthreads();
        int rank[8], bk[8];
        unsigned int pk[8];
#pragma unroll
        for (int j = 0; j < 8; j++) {
            int e = r0 + j * 256 + tid;
            bk[j] = -1;
            if (e < cend) {
                int d = dst[e];
                bk[j] = d >> BSHIFT;
                pk[j] = (unsigned int)src[e] | ((unsigned int)(d & (BNODES - 1)) << 17);
                rank[j] = atomicAdd(&cnt[bk[j]], 1);
            }
        }
        __syncthreads();
        if (tid < 128 && cnt[tid] > 0) base[tid] = atomicAdd(&gcur[tid], cnt[tid]);
        __syncthreads();
#pragma unroll
        for (int j = 0; j < 8; j++)
            if (bk[j] >= 0) ebuf[base[bk[j]] + rank[j]] = pk[j];
        __syncthreads();
    }
}

// Fused per-bucket: histogram -> degi/dinv -> LDS scan (local prefix) +
// bucket-base reduce over gcur -> rs -> scatter to csr (2nd ebuf pass is
// L2-resident). Replaces deg_hist, scan_part, scan_apply, csr_fill.
__global__ __launch_bounds__(256) void bucket_csr_kernel(
        const unsigned int* __restrict__ ebuf, const int* __restrict__ gcur,
        int* __restrict__ degi, float* __restrict__ dinv,
        int* __restrict__ rs, int* __restrict__ csr, int N) {
    __shared__ int h[BNODES];
    __shared__ int lp[BNODES];
    __shared__ int ps[256];
    int b = blockIdx.x;
    int t = threadIdx.x;
    int nb0 = b << BSHIFT;
    int nodes = min(BNODES, N - nb0);

    // bucket base = total edges in buckets < b
    int acc = 0;
    for (int j = t; j < b; j += 256) acc += gcur[j] - j * ECAP;
    ps[t] = acc;
    __syncthreads();
    for (int off = 128; off; off >>= 1) {
        if (t < off) ps[t] += ps[t + off];
        __syncthreads();
    }
    int bbase = ps[0];
    __syncthreads();

    // pass 1: histogram
    for (int i = t; i < BNODES; i += 256) h[i] = 0;
    __syncthreads();
    int estart = b * ECAP;
    int eend = gcur[b];
    for (int e = estart + t; e < eend; e += 256)
        atomicAdd(&h[ebuf[e] >> 17], 1);
    __syncthreads();

    // exclusive scan of h[0..1024) (4 elems/thread + block scan)
    int a0 = h[t * 4], a1 = h[t * 4 + 1], a2 = h[t * 4 + 2], a3 = h[t * 4 + 3];
    int tsum = a0 + a1 + a2 + a3;
    ps[t] = tsum;
    __syncthreads();
    for (int off = 1; off < 256; off <<= 1) {
        int u = (t >= off) ? ps[t - off] : 0;
        __syncthreads();
        ps[t] += u;
        __syncthreads();
    }
    int texcl = ps[t] - tsum;
    lp[t * 4]     = texcl;
    lp[t * 4 + 1] = texcl + a0;
    lp[t * 4 + 2] = texcl + a0 + a1;
    lp[t * 4 + 3] = texcl + a0 + a1 + a2;
    __syncthreads();

    // write degi/dinv/rs
    for (int i = t; i < nodes; i += 256) {
        int d = h[i];
        degi[nb0 + i] = d;
        dinv[nb0 + i] = rsqrtf((float)d + 1.0f);   // +1 = self loop
        rs[nb0 + i] = bbase + lp[i];
    }
    __syncthreads();
    // convert h -> global cursors
    for (int i = t; i < BNODES; i += 256) h[i] = bbase + lp[i];
    __syncthreads();

    // pass 2: scatter to csr (ebuf region ~144KB -> L2 hit)
    for (int e = estart + t; e < eend; e += 256) {
        unsigned int v = ebuf[e];
        int s = v & 0x1FFFF;
        int dl = v >> 17;
        int pos = atomicAdd(&h[dl], 1);
        csr[pos] = s;
    }
}

// Merged: blocks [0,424) transpose weights; blocks [424,..) quantize x.
// Xq = int8( 63.5 * dinv[row] * x )   (x is N x 128; 4 floats -> 1 uint)
__global__ __launch_bounds__(256) void wt_scale_kernel(
        const float* __restrict__ W0, const float* __restrict__ W1,
        const float* __restrict__ W2, u16* __restrict__ Wt0,
        u16* __restrict__ Wt1, u16* __restrict__ Wt2,
        const float* __restrict__ x, const float* __restrict__ dinv,
        unsigned int* __restrict__ out, int total4) {
    int b = blockIdx.x;
    if (b < 424) {
        int i = b * 256 + threadIdx.x;
        if (i < 32768) {                          // W0: 128x256
            int k = i >> 8, c = i & 255;
            Wt0[c * 128 + k] = f2bf(W0[i]);
        } else if (i < 98304) {                   // W1: 256x256
            int j = i - 32768;
            int k = j >> 8, c = j & 255;
            Wt1[c * 256 + k] = f2bf(W1[j]);
        } else if (i < 108544) {                  // W2: 256x40
            int j = i - 98304;
            int k = j / 40, c = j - k * 40;
            Wt2[c * 256 + k] = f2bf(W2[j]);
        }
        return;
    }
    int i = (b - 424) * 256 + threadIdx.x;
    if (i >= total4) return;
    int n = i >> 5;                       // 32 uints per row
    float4 v = reinterpret_cast<const float4*>(x)[i];
    float s = dinv[n] * 63.5f;
    int a0 = q8(v.x * s), a1 = q8(v.y * s), a2 = q8(v.z * s), a3 = q8(v.w * s);
    out[i] = (unsigned int)(a0 & 0xff) | ((unsigned int)(a1 & 0xff) << 8) |
             ((unsigned int)(a2 & 0xff) << 16) | ((unsigned int)(a3 & 0xff) << 24);
}

// accumulate one packed uint2 (8 int8 cols, already XORed) into 4 accumulators
#define ACC8(q0, q1)                                                  \
    do {                                                              \
        aex += (q0) & BMASK; aox += ((q0) >> 8) & BMASK;              \
        aey += (q1) & BMASK; aoy += ((q1) >> 8) & BMASK;              \
    } while (0)

// ---------------- layer-0 aggregation (int8 in, bf16 out, 128-wide) --------
// R19: wave-uniform row gathers -- readfirstlane -> SGPR base, ushort/lane
// (64x2B = one 128B row per load, saddr form), 16 rows in flight, masked tail.
__global__ __launch_bounds__(256) void agg128_i8_kernel(
        const signed char* __restrict__ in, u16* __restrict__ out,
        const int* __restrict__ rs, const int* __restrict__ deg,
        const int* __restrict__ csr, const float* __restrict__ dinv, int n) {
    int wid = blockIdx.x * 4 + (threadIdx.x >> 6);
    if (wid >= n) return;
    int lane = threadIdx.x & 63;
    int start = rs[wid];
    int cnt = deg[wid];

    unsigned int q = (unsigned int)*reinterpret_cast<const unsigned short*>(
        in + (size_t)wid * 128 + lane * 2) ^ 0x8080u;
    unsigned int ae = q & 0xFFu, ao = q >> 8;

    int i = 0;
    for (; i + 16 <= cnt; i += 16) {
        int s[16];
#pragma unroll
        for (int j = 0; j < 16; j++)
            s[j] = __builtin_amdgcn_readfirstlane(csr[start + i + j]);
        unsigned int qq[16];
#pragma unroll
        for (int j = 0; j < 16; j++)
            qq[j] = (unsigned int)*reinterpret_cast<const unsigned short*>(
                in + (size_t)s[j] * 128 + lane * 2);
#pragma unroll
        for (int j = 0; j < 16; j++) {
            unsigned int v = qq[j] ^ 0x8080u;
            ae += v & 0xFFu;
            ao += v >> 8;
        }
    }
    if (i < cnt) {              // masked 16-group tail, 16 still in flight
        int s[16];
#pragma unroll
        for (int j = 0; j < 16; j++) {
            int e = i + j;
            e = (e < cnt) ? e : (cnt - 1);
            s[j] = __builtin_amdgcn_readfirstlane(csr[start + e]);
        }
        unsigned int qq[16];
#pragma unroll
        for (int j = 0; j < 16; j++)
            qq[j] = (unsigned int)*reinterpret_cast<const unsigned short*>(
                in + (size_t)s[j] * 128 + lane * 2);
#pragma unroll
        for (int j = 0; j < 16; j++) {
            unsigned int m = (i + j < cnt) ? 0xFFFFu : 0u;
            unsigned int v = (qq[j] ^ 0x8080u) & m;
            ae += v & 0xFFu;
            ao += v >> 8;
        }
    }

    int bias = 128 * (cnt + 1);
    float c = dinv[wid] * (2.0f / 127.0f);
    float f0 = (float)((int)ae - bias) * c;
    float f1 = (float)((int)ao - bias) * c;
    reinterpret_cast<unsigned int*>(out + (size_t)wid * 128)[lane] =
        (unsigned)f2bf(f0) | ((unsigned)f2bf(f1) << 16);
}

// ---------------- layer-1 aggregation (int8 in, bf16 out, 256-wide) --------
// Wave-uniform row gathers (SGPR base), 16 rows in flight; masked tail.
__global__ __launch_bounds__(256) void agg_i8_kernel(
        const signed char* __restrict__ in, u16* __restrict__ out,
        const int* __restrict__ rs, const int* __restrict__ deg,
        const int* __restrict__ csr, const float* __restrict__ dinv, int n) {
    int wid = blockIdx.x * 4 + (threadIdx.x >> 6);
    if (wid >= n) return;
    int lane = threadIdx.x & 63;
    int start = rs[wid];
    int cnt = deg[wid];

    unsigned int q = *reinterpret_cast<const unsigned int*>(
        in + (size_t)wid * 256 + lane * 4) ^ 0x80808080u;
    unsigned int ae = q & BMASK, ao = (q >> 8) & BMASK;

    int i = 0;
    for (; i + 16 <= cnt; i += 16) {
        int s[16];
#pragma unroll
        for (int j = 0; j < 16; j++)
            s[j] = __builtin_amdgcn_readfirstlane(csr[start + i + j]);
        unsigned int qq[16];
#pragma unroll
        for (int j = 0; j < 16; j++)
            qq[j] = *reinterpret_cast<const unsigned int*>(
                in + (size_t)s[j] * 256 + lane * 4);
#pragma unroll
        for (int j = 0; j < 16; j++) {
            unsigned int v = qq[j] ^ 0x80808080u;
            ae += v & BMASK;
            ao += (v >> 8) & BMASK;
        }
    }
    if (i < cnt) {              // masked 16-group tail, 16 still in flight
        int s[16];
#pragma unroll
        for (int j = 0; j < 16; j++) {
            int e = i + j;
            e = (e < cnt) ? e : (cnt - 1);
            s[j] = __builtin_amdgcn_readfirstlane(csr[start + e]);
        }
        unsigned int qq[16];
#pragma unroll
        for (int j = 0; j < 16; j++)
            qq[j] = *reinterpret_cast<const unsigned int*>(
                in + (size_t)s[j] * 256 + lane * 4);
#pragma unroll
        for (int j = 0; j < 16; j++) {
            unsigned int m = (i + j < cnt) ? 0xFFFFFFFFu : 0u;
            unsigned int v = (qq[j] ^ 0x80808080u) & m;
            ae += v & BMASK;
            ao += (v >> 8) & BMASK;
        }
    }

    int bias = 128 * (cnt + 1);
    float c = dinv[wid] * (1.0f / 127.0f);
    float f0 = (float)((int)(ae & 0xFFFFu) - bias) * c;
    float f1 = (float)((int)(ao & 0xFFFFu) - bias) * c;
    float f2 = (float)((int)(ae >> 16) - bias) * c;
    float f3 = (float)((int)(ao >> 16) - bias) * c;
    uint2 o;
    o.x = (unsigned)f2bf(f0) | ((unsigned)f2bf(f1) << 16);
    o.y = (unsigned)f2bf(f2) | ((unsigned)f2bf(f3) << 16);
    reinterpret_cast<uint2*>(out + (size_t)wid * 256)[lane] = o;
}

// ---------------- MFMA matmul (R11 form: 128x64 tiles, 32-VGPR acc) --------
// NY=4: flat 1D grid, XCD-coherent swizzle -- ids {i,i+8,i+16,i+24} are the
// 4 col-blocks of one row-tile (same XCD via i%8 round-robin, same dispatch
// wave) -> A-tile L2-reused 4x. NY=1: plain 1D mapping.
template<int EPI, typename CT, int NY>
__global__ __launch_bounds__(256) void mfma_mm_kernel(
        const u16* __restrict__ A, const u16* __restrict__ Bt,
        CT* __restrict__ C, int M, int K, int NC,
        const float* __restrict__ bias, const float* __restrict__ postscale,
        float qs) {
    int row0, col0;
    if constexpr (NY == 1) {
        row0 = blockIdx.x * 128;
        col0 = 0;
    } else {
        int bid = blockIdx.x;
        int rb = bid >> 5, rem = bid & 31;
        int y = rem >> 3, s8 = rem & 7;
        int xb = rb * 8 + s8;
        row0 = xb * 128;
        col0 = y * 64;
        if (row0 >= M) return;   // tail guard (block-uniform)
    }

    __shared__ u16 As[128 * 40];
    __shared__ u16 Bs[64 * 40];
    int t = threadIdx.x;
    int w = t >> 6, lane = t & 63, quad = lane >> 4, l16 = lane & 15;

    f32x4 acc[2][4];
#pragma unroll
    for (int s = 0; s < 2; s++)
#pragma unroll
        for (int nb = 0; nb < 4; nb++)
            acc[s][nb] = (f32x4){0.f, 0.f, 0.f, 0.f};

    int bn = t >> 2, bkq = (t & 3) << 3;
    for (int k0 = 0; k0 < K; k0 += 32) {
#pragma unroll
        for (int i = t; i < 512; i += 256) {
            int r = i >> 2, c = (i & 3) << 3;
            int gr = row0 + r;
            uint4 v = {0u, 0u, 0u, 0u};
            if (gr < M)
                v = *reinterpret_cast<const uint4*>(A + (size_t)gr * K + k0 + c);
            *reinterpret_cast<uint4*>(&As[r * 40 + c]) = v;
        }
        {
            int gc = col0 + bn;
            uint4 v = {0u, 0u, 0u, 0u};
            if (gc < NC)
                v = *reinterpret_cast<const uint4*>(Bt + (size_t)gc * K + k0 + bkq);
            *reinterpret_cast<uint4*>(&Bs[bn * 40 + bkq]) = v;
        }
        __syncthreads();

        short8 af[2], bf[4];
        af[0] = *reinterpret_cast<const short8*>(&As[(w * 32 + l16) * 40 + quad * 8]);
        af[1] = *reinterpret_cast<const short8*>(&As[(w * 32 + 16 + l16) * 40 + quad * 8]);
#pragma unroll
        for (int nb = 0; nb < 4; nb++)
            bf[nb] = *reinterpret_cast<const short8*>(&Bs[(nb * 16 + l16) * 40 + quad * 8]);
#pragma unroll
        for (int s = 0; s < 2; s++)
#pragma unroll
            for (int nb = 0; nb < 4; nb++)
                acc[s][nb] = __builtin_amdgcn_mfma_f32_16x16x32_bf16(
                    af[s], bf[nb], acc[s][nb], 0, 0, 0);
        __syncthreads();
    }

#pragma unroll
    for (int s = 0; s < 2; s++) {
        int rbase = row0 + w * 32 + s * 16 + quad * 4;
#pragma unroll
        for (int nb = 0; nb < 4; nb++) {
            int gc = col0 + nb * 16 + l16;
#pragma unroll
            for (int r = 0; r < 4; r++) {
                int gr = rbase + r;
                if (gr >= M || gc >= NC) continue;
                float v = acc[s][nb][r];
                if constexpr (EPI == 1) v = tanhf(v + bias[gc]);
                else                    v = v * postscale[gr];
                if constexpr (sizeof(CT) == 1) {
                    float m = qs;
                    if constexpr (EPI == 1) m *= postscale[gr];
                    C[(size_t)gr * NC + gc] = (CT)q8(v * m);
                } else {
                    C[(size_t)gr * NC + gc] = (CT)f2bf(v);
                }
            }
        }
    }
}

// ---------------- final fused agg(40, int8) + bias + log_softmax -----------
__global__ __launch_bounds__(256) void agg40_ls_kernel(
        const signed char* __restrict__ in, const int* __restrict__ rs,
        const int* __restrict__ deg, const int* __restrict__ csr,
        const float* __restrict__ dinv, const float* __restrict__ bias,
        float* __restrict__ out, int n) {
    int wid = blockIdx.x * 4 + (threadIdx.x >> 6);
    if (wid >= n) return;
    int lane = threadIdx.x & 63;
    int grp = lane / 5;             // 0..12 (lanes 60..63 inactive)
    int l5 = lane - grp * 5;        // 0..4: which uint2 of the 40B row
    bool act = lane < 60;
    int start = rs[wid];
    int cnt = deg[wid];

    unsigned int aex = 0, aox = 0, aey = 0, aoy = 0;
    if (lane < 5) {                 // self row into group 0
        uint2 q = *reinterpret_cast<const uint2*>(
            in + (size_t)wid * 40 + l5 * 8);
        q.x ^= 0x80808080u; q.y ^= 0x80808080u;
        ACC8(q.x, q.y);
    }
    for (int base = 0; base < cnt; base += 12) {
        int e = base + grp;
        if (act && e < cnt) {
            int s0 = csr[start + e];
            uint2 q = *reinterpret_cast<const uint2*>(
                in + (size_t)s0 * 40 + l5 * 8);
            q.x ^= 0x80808080u; q.y ^= 0x80808080u;
            ACC8(q.x, q.y);
        }
    }
    // merge 12 groups -> group 0 (lanes 0..4)
    aex += (unsigned int)__shfl((int)aex, lane + 30);
    aox += (unsigned int)__shfl((int)aox, lane + 30);
    aey += (unsigned int)__shfl((int)aey, lane + 30);
    aoy += (unsigned int)__shfl((int)aoy, lane + 30);
    aex += (unsigned int)__shfl((int)aex, lane + 15);
    aox += (unsigned int)__shfl((int)aox, lane + 15);
    aey += (unsigned int)__shfl((int)aey, lane + 15);
    aoy += (unsigned int)__shfl((int)aoy, lane + 15);
    aex += (unsigned int)__shfl((int)aex, lane + 5) + (unsigned int)__shfl((int)aex, lane + 10);
    aox += (unsigned int)__shfl((int)aox, lane + 5) + (unsigned int)__shfl((int)aox, lane + 10);
    aey += (unsigned int)__shfl((int)aey, lane + 5) + (unsigned int)__shfl((int)aey, lane + 10);
    aoy += (unsigned int)__shfl((int)aoy, lane + 5) + (unsigned int)__shfl((int)aoy, lane + 10);

    bool act5 = lane < 5;
    float s = dinv[wid];
    float v0 = -INFINITY, v1 = -INFINITY, v2 = -INFINITY, v3 = -INFINITY;
    float v4 = -INFINITY, v5 = -INFINITY, v6 = -INFINITY, v7 = -INFINITY;
    if (act5) {
        int bb = 128 * (cnt + 1);
        float c = s * (1.0f / 63.0f);
        int cc = lane * 8;
        v0 = (float)((int)(aex & 0xFFFFu) - bb) * c + bias[cc + 0];
        v1 = (float)((int)(aox & 0xFFFFu) - bb) * c + bias[cc + 1];
        v2 = (float)((int)(aex >> 16) - bb) * c + bias[cc + 2];
        v3 = (float)((int)(aox >> 16) - bb) * c + bias[cc + 3];
        v4 = (float)((int)(aey & 0xFFFFu) - bb) * c + bias[cc + 4];
        v5 = (float)((int)(aoy & 0xFFFFu) - bb) * c + bias[cc + 5];
        v6 = (float)((int)(aey >> 16) - bb) * c + bias[cc + 6];
        v7 = (float)((int)(aoy >> 16) - bb) * c + bias[cc + 7];
    }
    float m = fmaxf(fmaxf(fmaxf(v0, v1), fmaxf(v2, v3)),
                    fmaxf(fmaxf(v4, v5), fmaxf(v6, v7)));
    for (int off = 4; off; off >>= 1) m = fmaxf(m, __shfl_xor(m, off));
    float e = 0.f;
    if (act5) e = __expf(v0 - m) + __expf(v1 - m) + __expf(v2 - m) + __expf(v3 - m)
                + __expf(v4 - m) + __expf(v5 - m) + __expf(v6 - m) + __expf(v7 - m);
    for (int off = 4; off; off >>= 1) e += __shfl_xor(e, off);
    float ls = logf(e);
    if (act5) {
        float4 o0, o1;
        o0.x = v0 - m - ls; o0.y = v1 - m - ls; o0.z = v2 - m - ls; o0.w = v3 - m - ls;
        o1.x = v4 - m - ls; o1.y = v5 - m - ls; o1.z = v6 - m - ls; o1.w = v7 - m - ls;
        float4* op = reinterpret_cast<float4*>(out + (size_t)wid * 40 + lane * 8);
        op[0] = o0;
        op[1] = o1;
    }
}

extern "C" void kernel_launch(void* const* d_in, const int* in_sizes, int n_in,
                              void* d_out, int out_size, void* d_ws, size_t ws_size,
                              hipStream_t stream) {
    const float* x  = (const float*)d_in[0];
    const int*   ei = (const int*)d_in[1];
    const float* W0 = (const float*)d_in[2];
    const float* b0 = (const float*)d_in[3];
    const float* W1 = (const float*)d_in[4];
    const float* b1 = (const float*)d_in[5];
    const float* W2 = (const float*)d_in[6];
    const float* b2 = (const float*)d_in[7];
    float* out = (float*)d_out;

    const int N = in_sizes[0] / 128;   // 100000
    const int E = in_sizes[1] / 2;     // 3200000
    const int IN = 128, H = 256, OUT = 40;
    const int NB = (N + BNODES - 1) >> BSHIFT;   // 98 buckets

    char* p = (char*)d_ws;
    auto carve = [&](size_t bytes) -> void* {
        void* r = (void*)p;
        p += (bytes + 255) & ~(size_t)255;
        return r;
    };
    float*        dinv = (float*)carve((size_t)N * 4);
    int*          degi = (int*)  carve((size_t)N * 4);
    int*          rs   = (int*)  carve((size_t)N * 4);
    int*          gcur = (int*)  carve((size_t)128 * 4);
    int*          csr  = (int*)  carve((size_t)E * 4);
    unsigned int* ebuf = (unsigned int*)carve((size_t)NB * ECAP * 4);   // 14.5 MB
    u16*          Wt0  = (u16*)  carve((size_t)IN * H * 2);
    u16*          Wt1  = (u16*)  carve((size_t)H * H * 2);
    u16*          Wt2  = (u16*)  carve((size_t)H * OUT * 2);
    u16*          U1   = (u16*)  carve((size_t)N * H * 2);    // 51.2 MB
    u16*          U2   = (u16*)  carve((size_t)N * H * 2);    // 51.2 MB

    // U1: Xq[0,12.8) + T0bf[12.8,38.4) -> T1bf[0,51.2) -> G2q[0,4)
    // U2: H0q[0,25.6) -> h1bf[0,51.2)
    signed char* Xq   = (signed char*)U1;
    u16*         T0bf = U1 + (size_t)N * IN / 2 + 64;   // after Xq
    signed char* H0q  = (signed char*)U2;
    u16*         T1bf = U1;
    u16*         h1bf = U2;
    signed char* G2q  = (signed char*)U1;

    const int* src = ei;
    const int* dst = ei + E;

    int gW = (N + 3) / 4;
    int gMM = (N + 127) / 128;
    int gA = (E + 8191) / 8192;
    int gG = ((gMM + 7) / 8) * 32;     // swizzled 1D grid for NY=4

    // ---- graph preprocessing ----
    init_gcur_kernel<<<1, 128, 0, stream>>>(gcur, NB);
    bucketize_kernel<<<gA, 256, 0, stream>>>(src, dst, gcur, ebuf, E);
    bucket_csr_kernel<<<NB, 256, 0, stream>>>(
        ebuf, gcur, degi, dinv, rs, csr, N);

    // ---- weights + layer-0 quantize (merged) ----
    int t4x = N * (IN / 4);
    wt_scale_kernel<<<424 + (t4x + 255) / 256, 256, 0, stream>>>(
        W0, W1, W2, Wt0, Wt1, Wt2, x, dinv, (unsigned int*)Xq, t4x);

    // ---- layer 0 ----
    agg128_i8_kernel<<<gW, 256, 0, stream>>>(Xq, T0bf, rs, degi, csr, dinv, N);
    // H0q = int8( 127 * dinv * tanh(T0@W0 + b0) )
    mfma_mm_kernel<1, signed char, 4><<<gG, 256, 0, stream>>>(
        T0bf, Wt0, H0q, N, IN, H, b0, dinv, 127.0f);

    // ---- layer 1 ----
    agg_i8_kernel<<<gW, 256, 0, stream>>>(H0q, T1bf, rs, degi, csr, dinv, N);
    mfma_mm_kernel<1, u16, 4><<<gG, 256, 0, stream>>>(
        T1bf, Wt1, h1bf, N, H, H, b1, nullptr, 0.f);

    // ---- layer 2 ----
    mfma_mm_kernel<0, signed char, 1><<<gMM, 256, 0, stream>>>(
        h1bf, Wt2, G2q, N, H, OUT, nullptr, dinv, 63.0f);
    agg40_ls_kernel<<<gW, 256, 0, stream>>>(G2q, rs, degi, csr, dinv, b2, out, N);
}

// Round 11
// 586.091 us; speedup vs baseline: 1.0253x; 1.0253x over previous
//
#include <hip/hip_runtime.h>
#include <hip/hip_bf16.h>
#include <cmath>

// ---------------------------------------------------------------------------
// GCN forward (R20 = R18 exactly):
//   R19's agg128 uniform-ushort gather regressed +14us (128B rows: payload
//   per instruction halves; quarter-split uint2 moves 512B/issue and wins
//   despite divergence). Reverted to R18's proven configuration (586.5us):
//   - agg_i8: wave-uniform uint gathers (256B row = full wave payload)
//   - agg128: quarter-split uint2 gathers (4 rows/issue)
//   - mm0/mm1: 128x64 tiles + XCD-coherent flat swizzle (A-tile L2-reuse 4x)
//   - fused preprocessing (bucket_csr), merged wt+scale launch
// ---------------------------------------------------------------------------

typedef unsigned short u16;
typedef __attribute__((ext_vector_type(8))) short short8;
typedef __attribute__((ext_vector_type(4))) float f32x4;

#define BSHIFT 10                   // 1024 nodes per bucket
#define BNODES (1 << BSHIFT)
#define ECAP   36864                // per-bucket edge capacity (mean ~32.7k)
#define BMASK 0x00FF00FFu

__device__ __forceinline__ u16 f2bf(float f) {
    unsigned int u = __float_as_uint(f);
    u += 0x7fffu + ((u >> 16) & 1u);        // round-to-nearest-even
    return (u16)(u >> 16);
}

__device__ __forceinline__ int q8(float v) {   // clip to [-127,127], round
    return (int)rintf(fminf(fmaxf(v, -127.0f), 127.0f));
}

// ---------------- graph preprocessing ----------------

__global__ __launch_bounds__(128) void init_gcur_kernel(
        int* __restrict__ gcur, int nb) {
    int b = blockIdx.x * 128 + threadIdx.x;
    if (b < nb) gcur[b] = b * ECAP;
}

// Phase A: group edges by bucket (dst>>BSHIFT) into fixed-capacity regions of
// ebuf, packed src|dstlow<<17. LDS ranks + one global atomic per bucket/round.
__global__ __launch_bounds__(256) void bucketize_kernel(
        const int* __restrict__ src, const int* __restrict__ dst,
        int* __restrict__ gcur, unsigned int* __restrict__ ebuf, int E) {
    __shared__ int cnt[128];
    __shared__ int base[128];
    int tid = threadIdx.x;
    int chunk0 = blockIdx.x * 8192;
    int cend = min(chunk0 + 8192, E);
    for (int r0 = chunk0; r0 < cend; r0 += 2048) {
        if (tid < 128) cnt[tid] = 0;
        __syncthreads();
        int rank[8], bk[8];
        unsigned int pk[8];
#pragma unroll
        for (int j = 0; j < 8; j++) {
            int e = r0 + j * 256 + tid;
            bk[j] = -1;
            if (e < cend) {
                int d = dst[e];
                bk[j] = d >> BSHIFT;
                pk[j] = (unsigned int)src[e] | ((unsigned int)(d & (BNODES - 1)) << 17);
                rank[j] = atomicAdd(&cnt[bk[j]], 1);
            }
        }
        __syncthreads();
        if (tid < 128 && cnt[tid] > 0) base[tid] = atomicAdd(&gcur[tid], cnt[tid]);
        __syncthreads();
#pragma unroll
        for (int j = 0; j < 8; j++)
            if (bk[j] >= 0) ebuf[base[bk[j]] + rank[j]] = pk[j];
        __syncthreads();
    }
}

// Fused per-bucket: histogram -> degi/dinv -> LDS scan (local prefix) +
// bucket-base reduce over gcur -> rs -> scatter to csr (2nd ebuf pass is
// L2-resident). Replaces deg_hist, scan_part, scan_apply, csr_fill.
__global__ __launch_bounds__(256) void bucket_csr_kernel(
        const unsigned int* __restrict__ ebuf, const int* __restrict__ gcur,
        int* __restrict__ degi, float* __restrict__ dinv,
        int* __restrict__ rs, int* __restrict__ csr, int N) {
    __shared__ int h[BNODES];
    __shared__ int lp[BNODES];
    __shared__ int ps[256];
    int b = blockIdx.x;
    int t = threadIdx.x;
    int nb0 = b << BSHIFT;
    int nodes = min(BNODES, N - nb0);

    // bucket base = total edges in buckets < b
    int acc = 0;
    for (int j = t; j < b; j += 256) acc += gcur[j] - j * ECAP;
    ps[t] = acc;
    __syncthreads();
    for (int off = 128; off; off >>= 1) {
        if (t < off) ps[t] += ps[t + off];
        __syncthreads();
    }
    int bbase = ps[0];
    __syncthreads();

    // pass 1: histogram
    for (int i = t; i < BNODES; i += 256) h[i] = 0;
    __syncthreads();
    int estart = b * ECAP;
    int eend = gcur[b];
    for (int e = estart + t; e < eend; e += 256)
        atomicAdd(&h[ebuf[e] >> 17], 1);
    __syncthreads();

    // exclusive scan of h[0..1024) (4 elems/thread + block scan)
    int a0 = h[t * 4], a1 = h[t * 4 + 1], a2 = h[t * 4 + 2], a3 = h[t * 4 + 3];
    int tsum = a0 + a1 + a2 + a3;
    ps[t] = tsum;
    __syncthreads();
    for (int off = 1; off < 256; off <<= 1) {
        int u = (t >= off) ? ps[t - off] : 0;
        __syncthreads();
        ps[t] += u;
        __syncthreads();
    }
    int texcl = ps[t] - tsum;
    lp[t * 4]     = texcl;
    lp[t * 4 + 1] = texcl + a0;
    lp[t * 4 + 2] = texcl + a0 + a1;
    lp[t * 4 + 3] = texcl + a0 + a1 + a2;
    __syncthreads();

    // write degi/dinv/rs
    for (int i = t; i < nodes; i += 256) {
        int d = h[i];
        degi[nb0 + i] = d;
        dinv[nb0 + i] = rsqrtf((float)d + 1.0f);   // +1 = self loop
        rs[nb0 + i] = bbase + lp[i];
    }
    __syncthreads();
    // convert h -> global cursors
    for (int i = t; i < BNODES; i += 256) h[i] = bbase + lp[i];
    __syncthreads();

    // pass 2: scatter to csr (ebuf region ~144KB -> L2 hit)
    for (int e = estart + t; e < eend; e += 256) {
        unsigned int v = ebuf[e];
        int s = v & 0x1FFFF;
        int dl = v >> 17;
        int pos = atomicAdd(&h[dl], 1);
        csr[pos] = s;
    }
}

// Merged: blocks [0,424) transpose weights; blocks [424,..) quantize x.
// Xq = int8( 63.5 * dinv[row] * x )   (x is N x 128; 4 floats -> 1 uint)
__global__ __launch_bounds__(256) void wt_scale_kernel(
        const float* __restrict__ W0, const float* __restrict__ W1,
        const float* __restrict__ W2, u16* __restrict__ Wt0,
        u16* __restrict__ Wt1, u16* __restrict__ Wt2,
        const float* __restrict__ x, const float* __restrict__ dinv,
        unsigned int* __restrict__ out, int total4) {
    int b = blockIdx.x;
    if (b < 424) {
        int i = b * 256 + threadIdx.x;
        if (i < 32768) {                          // W0: 128x256
            int k = i >> 8, c = i & 255;
            Wt0[c * 128 + k] = f2bf(W0[i]);
        } else if (i < 98304) {                   // W1: 256x256
            int j = i - 32768;
            int k = j >> 8, c = j & 255;
            Wt1[c * 256 + k] = f2bf(W1[j]);
        } else if (i < 108544) {                  // W2: 256x40
            int j = i - 98304;
            int k = j / 40, c = j - k * 40;
            Wt2[c * 256 + k] = f2bf(W2[j]);
        }
        return;
    }
    int i = (b - 424) * 256 + threadIdx.x;
    if (i >= total4) return;
    int n = i >> 5;                       // 32 uints per row
    float4 v = reinterpret_cast<const float4*>(x)[i];
    float s = dinv[n] * 63.5f;
    int a0 = q8(v.x * s), a1 = q8(v.y * s), a2 = q8(v.z * s), a3 = q8(v.w * s);
    out[i] = (unsigned int)(a0 & 0xff) | ((unsigned int)(a1 & 0xff) << 8) |
             ((unsigned int)(a2 & 0xff) << 16) | ((unsigned int)(a3 & 0xff) << 24);
}

// accumulate one packed uint2 (8 int8 cols, already XORed) into 4 accumulators
#define ACC8(q0, q1)                                                  \
    do {                                                              \
        aex += (q0) & BMASK; aox += ((q0) >> 8) & BMASK;              \
        aey += (q1) & BMASK; aoy += ((q1) >> 8) & BMASK;              \
    } while (0)

// ---------------- layer-0 aggregation (int8 in, bf16 out, 128-wide) --------
// Quarter-split: 16-lane quarters x uint2 -> 4 rows (512B) per issue,
// unroll 4 -> 16 edges in flight.
__global__ __launch_bounds__(256) void agg128_i8_kernel(
        const signed char* __restrict__ in, u16* __restrict__ out,
        const int* __restrict__ rs, const int* __restrict__ deg,
        const int* __restrict__ csr, const float* __restrict__ dinv, int n) {
    int wid = blockIdx.x * 4 + (threadIdx.x >> 6);
    if (wid >= n) return;
    int lane = threadIdx.x & 63;
    int quad = lane >> 4;       // which edge of the group of 4
    int l16 = lane & 15;        // which uint2 of the 128B row
    int start = rs[wid];
    int cnt = deg[wid];

    unsigned int aex = 0, aox = 0, aey = 0, aoy = 0;
    if (quad == 0) {            // self row into quarter 0
        uint2 q = *reinterpret_cast<const uint2*>(
            in + (size_t)wid * 128 + l16 * 8);
        q.x ^= 0x80808080u; q.y ^= 0x80808080u;
        ACC8(q.x, q.y);
    }
    int i = 0;
    for (; i + 16 <= cnt; i += 16) {
        int s[4];
#pragma unroll
        for (int j = 0; j < 4; j++) s[j] = csr[start + i + 4 * j + quad];
#pragma unroll
        for (int j = 0; j < 4; j++) {
            uint2 q = *reinterpret_cast<const uint2*>(
                in + (size_t)s[j] * 128 + l16 * 8);
            q.x ^= 0x80808080u; q.y ^= 0x80808080u;
            ACC8(q.x, q.y);
        }
    }
    for (; i + 4 <= cnt; i += 4) {
        int s0 = csr[start + i + quad];
        uint2 q = *reinterpret_cast<const uint2*>(
            in + (size_t)s0 * 128 + l16 * 8);
        q.x ^= 0x80808080u; q.y ^= 0x80808080u;
        ACC8(q.x, q.y);
    }
    int rem = cnt - i;
    if (quad < rem) {
        int s0 = csr[start + i + quad];
        uint2 q = *reinterpret_cast<const uint2*>(
            in + (size_t)s0 * 128 + l16 * 8);
        q.x ^= 0x80808080u; q.y ^= 0x80808080u;
        ACC8(q.x, q.y);
    }
    // merge the 4 quarters (valid for lanes < 16)
    aex += (unsigned int)__shfl((int)aex, lane + 32);
    aox += (unsigned int)__shfl((int)aox, lane + 32);
    aey += (unsigned int)__shfl((int)aey, lane + 32);
    aoy += (unsigned int)__shfl((int)aoy, lane + 32);
    aex += (unsigned int)__shfl((int)aex, lane + 16);
    aox += (unsigned int)__shfl((int)aox, lane + 16);
    aey += (unsigned int)__shfl((int)aey, lane + 16);
    aoy += (unsigned int)__shfl((int)aoy, lane + 16);
    if (lane < 16) {
        int T = cnt + 1;
        int bias = 128 * T;
        float c = dinv[wid] * (2.0f / 127.0f);
        float f0 = (float)((int)(aex & 0xFFFFu) - bias) * c;
        float f1 = (float)((int)(aox & 0xFFFFu) - bias) * c;
        float f2 = (float)((int)(aex >> 16) - bias) * c;
        float f3 = (float)((int)(aox >> 16) - bias) * c;
        float f4 = (float)((int)(aey & 0xFFFFu) - bias) * c;
        float f5 = (float)((int)(aoy & 0xFFFFu) - bias) * c;
        float f6 = (float)((int)(aey >> 16) - bias) * c;
        float f7 = (float)((int)(aoy >> 16) - bias) * c;
        uint4 o;
        o.x = (unsigned)f2bf(f0) | ((unsigned)f2bf(f1) << 16);
        o.y = (unsigned)f2bf(f2) | ((unsigned)f2bf(f3) << 16);
        o.z = (unsigned)f2bf(f4) | ((unsigned)f2bf(f5) << 16);
        o.w = (unsigned)f2bf(f6) | ((unsigned)f2bf(f7) << 16);
        reinterpret_cast<uint4*>(out + (size_t)wid * 128)[l16] = o;
    }
}

// ---------------- layer-1 aggregation (int8 in, bf16 out, 256-wide) --------
// Wave-uniform row gathers (SGPR base), 16 rows in flight; masked tail.
__global__ __launch_bounds__(256) void agg_i8_kernel(
        const signed char* __restrict__ in, u16* __restrict__ out,
        const int* __restrict__ rs, const int* __restrict__ deg,
        const int* __restrict__ csr, const float* __restrict__ dinv, int n) {
    int wid = blockIdx.x * 4 + (threadIdx.x >> 6);
    if (wid >= n) return;
    int lane = threadIdx.x & 63;
    int start = rs[wid];
    int cnt = deg[wid];

    unsigned int q = *reinterpret_cast<const unsigned int*>(
        in + (size_t)wid * 256 + lane * 4) ^ 0x80808080u;
    unsigned int ae = q & BMASK, ao = (q >> 8) & BMASK;

    int i = 0;
    for (; i + 16 <= cnt; i += 16) {
        int s[16];
#pragma unroll
        for (int j = 0; j < 16; j++)
            s[j] = __builtin_amdgcn_readfirstlane(csr[start + i + j]);
        unsigned int qq[16];
#pragma unroll
        for (int j = 0; j < 16; j++)
            qq[j] = *reinterpret_cast<const unsigned int*>(
                in + (size_t)s[j] * 256 + lane * 4);
#pragma unroll
        for (int j = 0; j < 16; j++) {
            unsigned int v = qq[j] ^ 0x80808080u;
            ae += v & BMASK;
            ao += (v >> 8) & BMASK;
        }
    }
    if (i < cnt) {              // masked 16-group tail, 16 still in flight
        int s[16];
#pragma unroll
        for (int j = 0; j < 16; j++) {
            int e = i + j;
            e = (e < cnt) ? e : (cnt - 1);
            s[j] = __builtin_amdgcn_readfirstlane(csr[start + e]);
        }
        unsigned int qq[16];
#pragma unroll
        for (int j = 0; j < 16; j++)
            qq[j] = *reinterpret_cast<const unsigned int*>(
                in + (size_t)s[j] * 256 + lane * 4);
#pragma unroll
        for (int j = 0; j < 16; j++) {
            unsigned int m = (i + j < cnt) ? 0xFFFFFFFFu : 0u;
            unsigned int v = (qq[j] ^ 0x80808080u) & m;
            ae += v & BMASK;
            ao += (v >> 8) & BMASK;
        }
    }

    int bias = 128 * (cnt + 1);
    float c = dinv[wid] * (1.0f / 127.0f);
    float f0 = (float)((int)(ae & 0xFFFFu) - bias) * c;
    float f1 = (float)((int)(ao & 0xFFFFu) - bias) * c;
    float f2 = (float)((int)(ae >> 16) - bias) * c;
    float f3 = (float)((int)(ao >> 16) - bias) * c;
    uint2 o;
    o.x = (unsigned)f2bf(f0) | ((unsigned)f2bf(f1) << 16);
    o.y = (unsigned)f2bf(f2) | ((unsigned)f2bf(f3) << 16);
    reinterpret_cast<uint2*>(out + (size_t)wid * 256)[lane] = o;
}

// ---------------- MFMA matmul (R11 form: 128x64 tiles, 32-VGPR acc) --------
// NY=4: flat 1D grid, XCD-coherent swizzle -- ids {i,i+8,i+16,i+24} are the
// 4 col-blocks of one row-tile (same XCD via i%8 round-robin, same dispatch
// wave) -> A-tile L2-reused 4x. NY=1: plain 1D mapping.
template<int EPI, typename CT, int NY>
__global__ __launch_bounds__(256) void mfma_mm_kernel(
        const u16* __restrict__ A, const u16* __restrict__ Bt,
        CT* __restrict__ C, int M, int K, int NC,
        const float* __restrict__ bias, const float* __restrict__ postscale,
        float qs) {
    int row0, col0;
    if constexpr (NY == 1) {
        row0 = blockIdx.x * 128;
        col0 = 0;
    } else {
        int bid = blockIdx.x;
        int rb = bid >> 5, rem = bid & 31;
        int y = rem >> 3, s8 = rem & 7;
        int xb = rb * 8 + s8;
        row0 = xb * 128;
        col0 = y * 64;
        if (row0 >= M) return;   // tail guard (block-uniform)
    }

    __shared__ u16 As[128 * 40];
    __shared__ u16 Bs[64 * 40];
    int t = threadIdx.x;
    int w = t >> 6, lane = t & 63, quad = lane >> 4, l16 = lane & 15;

    f32x4 acc[2][4];
#pragma unroll
    for (int s = 0; s < 2; s++)
#pragma unroll
        for (int nb = 0; nb < 4; nb++)
            acc[s][nb] = (f32x4){0.f, 0.f, 0.f, 0.f};

    int bn = t >> 2, bkq = (t & 3) << 3;
    for (int k0 = 0; k0 < K; k0 += 32) {
#pragma unroll
        for (int i = t; i < 512; i += 256) {
            int r = i >> 2, c = (i & 3) << 3;
            int gr = row0 + r;
            uint4 v = {0u, 0u, 0u, 0u};
            if (gr < M)
                v = *reinterpret_cast<const uint4*>(A + (size_t)gr * K + k0 + c);
            *reinterpret_cast<uint4*>(&As[r * 40 + c]) = v;
        }
        {
            int gc = col0 + bn;
            uint4 v = {0u, 0u, 0u, 0u};
            if (gc < NC)
                v = *reinterpret_cast<const uint4*>(Bt + (size_t)gc * K + k0 + bkq);
            *reinterpret_cast<uint4*>(&Bs[bn * 40 + bkq]) = v;
        }
        __syncthreads();

        short8 af[2], bf[4];
        af[0] = *reinterpret_cast<const short8*>(&As[(w * 32 + l16) * 40 + quad * 8]);
        af[1] = *reinterpret_cast<const short8*>(&As[(w * 32 + 16 + l16) * 40 + quad * 8]);
#pragma unroll
        for (int nb = 0; nb < 4; nb++)
            bf[nb] = *reinterpret_cast<const short8*>(&Bs[(nb * 16 + l16) * 40 + quad * 8]);
#pragma unroll
        for (int s = 0; s < 2; s++)
#pragma unroll
            for (int nb = 0; nb < 4; nb++)
                acc[s][nb] = __builtin_amdgcn_mfma_f32_16x16x32_bf16(
                    af[s], bf[nb], acc[s][nb], 0, 0, 0);
        __syncthreads();
    }

#pragma unroll
    for (int s = 0; s < 2; s++) {
        int rbase = row0 + w * 32 + s * 16 + quad * 4;
#pragma unroll
        for (int nb = 0; nb < 4; nb++) {
            int gc = col0 + nb * 16 + l16;
#pragma unroll
            for (int r = 0; r < 4; r++) {
                int gr = rbase + r;
                if (gr >= M || gc >= NC) continue;
                float v = acc[s][nb][r];
                if constexpr (EPI == 1) v = tanhf(v + bias[gc]);
                else                    v = v * postscale[gr];
                if constexpr (sizeof(CT) == 1) {
                    float m = qs;
                    if constexpr (EPI == 1) m *= postscale[gr];
                    C[(size_t)gr * NC + gc] = (CT)q8(v * m);
                } else {
                    C[(size_t)gr * NC + gc] = (CT)f2bf(v);
                }
            }
        }
    }
}

// ---------------- final fused agg(40, int8) + bias + log_softmax -----------
__global__ __launch_bounds__(256) void agg40_ls_kernel(
        const signed char* __restrict__ in, const int* __restrict__ rs,
        const int* __restrict__ deg, const int* __restrict__ csr,
        const float* __restrict__ dinv, const float* __restrict__ bias,
        float* __restrict__ out, int n) {
    int wid = blockIdx.x * 4 + (threadIdx.x >> 6);
    if (wid >= n) return;
    int lane = threadIdx.x & 63;
    int grp = lane / 5;             // 0..12 (lanes 60..63 inactive)
    int l5 = lane - grp * 5;        // 0..4: which uint2 of the 40B row
    bool act = lane < 60;
    int start = rs[wid];
    int cnt = deg[wid];

    unsigned int aex = 0, aox = 0, aey = 0, aoy = 0;
    if (lane < 5) {                 // self row into group 0
        uint2 q = *reinterpret_cast<const uint2*>(
            in + (size_t)wid * 40 + l5 * 8);
        q.x ^= 0x80808080u; q.y ^= 0x80808080u;
        ACC8(q.x, q.y);
    }
    for (int base = 0; base < cnt; base += 12) {
        int e = base + grp;
        if (act && e < cnt) {
            int s0 = csr[start + e];
            uint2 q = *reinterpret_cast<const uint2*>(
                in + (size_t)s0 * 40 + l5 * 8);
            q.x ^= 0x80808080u; q.y ^= 0x80808080u;
            ACC8(q.x, q.y);
        }
    }
    // merge 12 groups -> group 0 (lanes 0..4)
    aex += (unsigned int)__shfl((int)aex, lane + 30);
    aox += (unsigned int)__shfl((int)aox, lane + 30);
    aey += (unsigned int)__shfl((int)aey, lane + 30);
    aoy += (unsigned int)__shfl((int)aoy, lane + 30);
    aex += (unsigned int)__shfl((int)aex, lane + 15);
    aox += (unsigned int)__shfl((int)aox, lane + 15);
    aey += (unsigned int)__shfl((int)aey, lane + 15);
    aoy += (unsigned int)__shfl((int)aoy, lane + 15);
    aex += (unsigned int)__shfl((int)aex, lane + 5) + (unsigned int)__shfl((int)aex, lane + 10);
    aox += (unsigned int)__shfl((int)aox, lane + 5) + (unsigned int)__shfl((int)aox, lane + 10);
    aey += (unsigned int)__shfl((int)aey, lane + 5) + (unsigned int)__shfl((int)aey, lane + 10);
    aoy += (unsigned int)__shfl((int)aoy, lane + 5) + (unsigned int)__shfl((int)aoy, lane + 10);

    bool act5 = lane < 5;
    float s = dinv[wid];
    float v0 = -INFINITY, v1 = -INFINITY, v2 = -INFINITY, v3 = -INFINITY;
    float v4 = -INFINITY, v5 = -INFINITY, v6 = -INFINITY, v7 = -INFINITY;
    if (act5) {
        int bb = 128 * (cnt + 1);
        float c = s * (1.0f / 63.0f);
        int cc = lane * 8;
        v0 = (float)((int)(aex & 0xFFFFu) - bb) * c + bias[cc + 0];
        v1 = (float)((int)(aox & 0xFFFFu) - bb) * c + bias[cc + 1];
        v2 = (float)((int)(aex >> 16) - bb) * c + bias[cc + 2];
        v3 = (float)((int)(aox >> 16) - bb) * c + bias[cc + 3];
        v4 = (float)((int)(aey & 0xFFFFu) - bb) * c + bias[cc + 4];
        v5 = (float)((int)(aoy & 0xFFFFu) - bb) * c + bias[cc + 5];
        v6 = (float)((int)(aey >> 16) - bb) * c + bias[cc + 6];
        v7 = (float)((int)(aoy >> 16) - bb) * c + bias[cc + 7];
    }
    float m = fmaxf(fmaxf(fmaxf(v0, v1), fmaxf(v2, v3)),
                    fmaxf(fmaxf(v4, v5), fmaxf(v6, v7)));
    for (int off = 4; off; off >>= 1) m = fmaxf(m, __shfl_xor(m, off));
    float e = 0.f;
    if (act5) e = __expf(v0 - m) + __expf(v1 - m) + __expf(v2 - m) + __expf(v3 - m)
                + __expf(v4 - m) + __expf(v5 - m) + __expf(v6 - m) + __expf(v7 - m);
    for (int off = 4; off; off >>= 1) e += __shfl_xor(e, off);
    float ls = logf(e);
    if (act5) {
        float4 o0, o1;
        o0.x = v0 - m - ls; o0.y = v1 - m - ls; o0.z = v2 - m - ls; o0.w = v3 - m - ls;
        o1.x = v4 - m - ls; o1.y = v5 - m - ls; o1.z = v6 - m - ls; o1.w = v7 - m - ls;
        float4* op = reinterpret_cast<float4*>(out + (size_t)wid * 40 + lane * 8);
        op[0] = o0;
        op[1] = o1;
    }
}

extern "C" void kernel_launch(void* const* d_in, const int* in_sizes, int n_in,
                              void* d_out, int out_size, void* d_ws, size_t ws_size,
                              hipStream_t stream) {
    const float* x  = (const float*)d_in[0];
    const int*   ei = (const int*)d_in[1];
    const float* W0 = (const float*)d_in[2];
    const float* b0 = (const float*)d_in[3];
    const float* W1 = (const float*)d_in[4];
    const float* b1 = (const float*)d_in[5];
    const float* W2 = (const float*)d_in[6];
    const float* b2 = (const float*)d_in[7];
    float* out = (float*)d_out;

    const int N = in_sizes[0] / 128;   // 100000
    const int E = in_sizes[1] / 2;     // 3200000
    const int IN = 128, H = 256, OUT = 40;
    const int NB = (N + BNODES - 1) >> BSHIFT;   // 98 buckets

    char* p = (char*)d_ws;
    auto carve = [&](size_t bytes) -> void* {
        void* r = (void*)p;
        p += (bytes + 255) & ~(size_t)255;
        return r;
    };
    float*        dinv = (float*)carve((size_t)N * 4);
    int*          degi = (int*)  carve((size_t)N * 4);
    int*          rs   = (int*)  carve((size_t)N * 4);
    int*          gcur = (int*)  carve((size_t)128 * 4);
    int*          csr  = (int*)  carve((size_t)E * 4);
    unsigned int* ebuf = (unsigned int*)carve((size_t)NB * ECAP * 4);   // 14.5 MB
    u16*          Wt0  = (u16*)  carve((size_t)IN * H * 2);
    u16*          Wt1  = (u16*)  carve((size_t)H * H * 2);
    u16*          Wt2  = (u16*)  carve((size_t)H * OUT * 2);
    u16*          U1   = (u16*)  carve((size_t)N * H * 2);    // 51.2 MB
    u16*          U2   = (u16*)  carve((size_t)N * H * 2);    // 51.2 MB

    // U1: Xq[0,12.8) + T0bf[12.8,38.4) -> T1bf[0,51.2) -> G2q[0,4)
    // U2: H0q[0,25.6) -> h1bf[0,51.2)
    signed char* Xq   = (signed char*)U1;
    u16*         T0bf = U1 + (size_t)N * IN / 2 + 64;   // after Xq
    signed char* H0q  = (signed char*)U2;
    u16*         T1bf = U1;
    u16*         h1bf = U2;
    signed char* G2q  = (signed char*)U1;

    const int* src = ei;
    const int* dst = ei + E;

    int gW = (N + 3) / 4;
    int gMM = (N + 127) / 128;
    int gA = (E + 8191) / 8192;
    int gG = ((gMM + 7) / 8) * 32;     // swizzled 1D grid for NY=4

    // ---- graph preprocessing ----
    init_gcur_kernel<<<1, 128, 0, stream>>>(gcur, NB);
    bucketize_kernel<<<gA, 256, 0, stream>>>(src, dst, gcur, ebuf, E);
    bucket_csr_kernel<<<NB, 256, 0, stream>>>(
        ebuf, gcur, degi, dinv, rs, csr, N);

    // ---- weights + layer-0 quantize (merged) ----
    int t4x = N * (IN / 4);
    wt_scale_kernel<<<424 + (t4x + 255) / 256, 256, 0, stream>>>(
        W0, W1, W2, Wt0, Wt1, Wt2, x, dinv, (unsigned int*)Xq, t4x);

    // ---- layer 0 ----
    agg128_i8_kernel<<<gW, 256, 0, stream>>>(Xq, T0bf, rs, degi, csr, dinv, N);
    // H0q = int8( 127 * dinv * tanh(T0@W0 + b0) )
    mfma_mm_kernel<1, signed char, 4><<<gG, 256, 0, stream>>>(
        T0bf, Wt0, H0q, N, IN, H, b0, dinv, 127.0f);

    // ---- layer 1 ----
    agg_i8_kernel<<<gW, 256, 0, stream>>>(H0q, T1bf, rs, degi, csr, dinv, N);
    mfma_mm_kernel<1, u16, 4><<<gG, 256, 0, stream>>>(
        T1bf, Wt1, h1bf, N, H, H, b1, nullptr, 0.f);

    // ---- layer 2 ----
    mfma_mm_kernel<0, signed char, 1><<<gMM, 256, 0, stream>>>(
        h1bf, Wt2, G2q, N, H, OUT, nullptr, dinv, 63.0f);
    agg40_ls_kernel<<<gW, 256, 0, stream>>>(G2q, rs, degi, csr, dinv, b2, out, N);
}